// Round 4
// baseline (630.832 us; speedup 1.0000x reference)
//
#include <hip/hip_runtime.h>

// 3x3 reflect-padded patch extraction.
// x: [8, 256, 256, 32] f32  ->  out: [8, 256, 256, 288] f32
// out[b,h,w, c*9 + i] = x[b, refl(h + i/3 - 1), refl(w + i%3 - 1), c]
//
// v6: persistent row-streaming blocks.
//  - 2048 blocks; each owns a HALF ROW-PAIR: 4 consecutive w-tiles of one
//    (b, h, h+1). The 4 input row bases are fixed for the whole block, so
//    after iteration 0 every tap load is L1-hot (same rows, sliding window).
//    Steady-state HBM traffic becomes a near-pure write stream (fill-like),
//    instead of 16K one-shot blocks each paying cold-load latency at the
//    head and a vmcnt(0) store-drain at the tail.
//  - no barrier anywhere: LDS transpose stays wave-private (rows 8wv..8wv+7,
//    in-order per-wave DS pipe makes write->read and read->next-write safe;
//    validated absmax=0 in v4b/v5). Compiler is free to hoist iteration t+1
//    loads above iteration t stores (__restrict__ no-alias).
//  - LDS 36864B -> 4 blocks/CU resident, 8 queued per CU (2 rounds, some
//    rebalance slack). __launch_bounds__(256,4) caps VGPR at 128 so
//    occupancy stays LDS-capped (16 waves/CU), not VGPR-capped.
//  - nontemporal coalesced float4 stores (write-once output, keep L2 for
//    the resident input rows).

#define BB 8
#define HH 256
#define WW 256
#define CC 32
#define TAPS 9
#define OUTC (CC * TAPS)    // 288
#define TW 32               // w-tile width
#define TPB 4               // w-tiles per block (half a row)
#define NBLK (BB * (HH / 2) * 2)   // 2048: b x h-pair x half

typedef float f32x4 __attribute__((ext_vector_type(4)));

__device__ __forceinline__ int refl(int i, int n) {
    // np.pad mode='reflect', valid for i in [-1, n]
    return i < 0 ? -i : (i >= n ? 2 * n - 2 - i : i);
}

__global__ __launch_bounds__(256, 4) void patch3x3_v6(
    const float* __restrict__ x, float* __restrict__ out) {
    const int blk  = blockIdx.x;
    const int half = blk & 1;                  // which half-row
    const int hb   = (blk >> 1) & (HH / 2 - 1);
    const int b    = blk >> 8;
    const int h    = hb * 2;
    const int t    = threadIdx.x;

    __shared__ float out_lds[TW][OUTC];        // 36864 B

    const int p  = t >> 3;      // pixel in tile, 0..31 (wave wv owns 8wv..8wv+7)
    const int cg = t & 7;       // channel group of 4, 0..7
    const int wv = t >> 6;
    const int l  = t & 63;

    // ---- four input row bases, fixed for the whole block ----
    const float* xb = x + (size_t)b * HH * WW * CC;
    const float* rowp0 = xb + (size_t)refl(h - 1, HH) * WW * CC;
    const float* rowp1 = xb + (size_t)h * WW * CC;
    const float* rowp2 = xb + (size_t)(h + 1) * WW * CC;
    const float* rowp3 = xb + (size_t)refl(h + 2, HH) * WW * CC;

    for (int it = 0; it < TPB; ++it) {
        const int w0 = (half * TPB + it) * TW;

        int coff[3];
#pragma unroll
        for (int kj = 0; kj < 3; ++kj)
            coff[kj] = refl(w0 + p + kj - 1, WW) * CC + cg * 4;

        // ---- tap loads: L1-hot after it==0 (same 4 rows, sliding window) ----
        f32x4 Q[4][3];
#pragma unroll
        for (int kj = 0; kj < 3; ++kj) {
            Q[0][kj] = *(const f32x4*)(rowp0 + coff[kj]);
            Q[1][kj] = *(const f32x4*)(rowp1 + coff[kj]);
            Q[2][kj] = *(const f32x4*)(rowp2 + coff[kj]);
            Q[3][kj] = *(const f32x4*)(rowp3 + coff[kj]);
        }

        // ---- two output rows from the register window ----
#pragma unroll
        for (int ph = 0; ph < 2; ++ph) {
            // repack (pure register selects) + LDS write in output layout
            // local flat f = cl*9 + i, cl in [0,4), i = 3*ki + kj
#pragma unroll
            for (int m = 0; m < 9; ++m) {
                f32x4 v;
#pragma unroll
                for (int k = 0; k < 4; ++k) {
                    const int f  = 4 * m + k;   // compile-time
                    const int cl = f / 9;
                    const int i  = f % 9;
                    const int ki = i / 3;
                    const int kj = i % 3;
                    v[k] = Q[ph + ki][kj][cl];
                }
                *(f32x4*)&out_lds[p][cg * 36 + 4 * m] = v;
            }

            // wave reads back only its own quadrant; no barrier needed
            f32x4* outp = (f32x4*)(out +
                (size_t)((b * HH + h + ph) * WW + w0) * OUTC);
            const f32x4* src4 = (const f32x4*)&out_lds[0][0];
#pragma unroll
            for (int s = 0; s < TAPS; ++s) {        // 9 iters, 1KB/wave each
                const int idx = wv * 576 + 64 * s + l;
                __builtin_nontemporal_store(src4[idx], &outp[idx]);
            }

            // compiler-only fence: keep the next phase's ds_writes from
            // moving above this phase's ds_reads (HW DS pipe is in-order).
            asm volatile("" ::: "memory");
        }
    }
}

extern "C" void kernel_launch(void* const* d_in, const int* in_sizes, int n_in,
                              void* d_out, int out_size, void* d_ws, size_t ws_size,
                              hipStream_t stream) {
    const float* x = (const float*)d_in[0];
    float* out = (float*)d_out;
    patch3x3_v6<<<NBLK, 256, 0, stream>>>(x, out);
}